// Round 1
// baseline (548.860 us; speedup 1.0000x reference)
//
#include <hip/hip_runtime.h>
#include <stdint.h>

// Problem constants (N,C,H,W fixed by the reference)
#define NB 32
#define CH 256
#define HH 56
#define WW 56
#define HWSZ (HH*WW)            // 3136
#define NPIX (NB*HWSZ)          // 100352 = 392*256 exactly
#define HP 58
#define WP 58
#define PADPIX (NB*HP*WP)       // 107648
#define NWORDS 8                // 256 channels / 32 bits
#define NTAPS 9
#define KKE (CH*NTAPS)          // 2304
#define NPIXD 100352.0

// ---------------- init: zero atomics accumulators ----------------
__global__ void init_kernel(long long* __restrict__ sums, uint32_t* __restrict__ wzany) {
    int t = blockIdx.x*256 + threadIdx.x;
    if (t < 1024) sums[t] = 0;     // 2 convs x 256 ch x {sum,sumsq}
    if (t < 288)  wzany[t] = 0;    // 2 convs x 9 taps x 16 o-blocks
}

// ---------------- pack weights into bit-words ----------------
// wb[conv][tap][o][wd]: bit j = 1 iff w(o, 32*wd+j, tap) < 0   (xnor trick: s ^ wb)
// wz: bit = 1 iff w == 0 exactly (rare; corrected in conv via wzany flag)
__global__ void packw_kernel(const float* __restrict__ w1, const float* __restrict__ w2,
                             uint32_t* __restrict__ wb, uint32_t* __restrict__ wz,
                             uint32_t* __restrict__ wzany) {
    int t = blockIdx.x*256 + threadIdx.x;          // 72 blocks -> 18432 = 9*256*8
    if (t >= NTAPS*CH*NWORDS) return;
    int conv = blockIdx.y;
    const float* w = conv ? w2 : w1;
    int wd  = t & 7;
    int o   = (t >> 3) & 255;
    int tap = t >> 11;
    uint32_t nb = 0, zb = 0;
    for (int j = 0; j < 32; ++j) {
        float v = w[(size_t)(o*CH + wd*32 + j)*NTAPS + tap];
        if (v < 0.f)  nb |= 1u << j;
        if (v == 0.f) zb |= 1u << j;
    }
    size_t base = (size_t)conv*NTAPS*CH*NWORDS;
    wb[base + t] = nb;             // t == (tap*256 + o)*8 + wd
    wz[base + t] = zb;
    if (zb) atomicOr(&wzany[conv*NTAPS*16 + tap*16 + (o >> 4)], 1u);
}

// ---------------- alpha[o] = mean |w| over (I,3,3) ----------------
__global__ void alpha_kernel(const float* __restrict__ w1, const float* __restrict__ w2,
                             float* __restrict__ alpha) {
    int o = blockIdx.x; int conv = blockIdx.y;
    const float* w = conv ? w2 : w1;
    float s = 0.f;
    for (int i = threadIdx.x; i < KKE; i += 256) s += fabsf(w[(size_t)o*KKE + i]);
    for (int off = 32; off; off >>= 1) s += __shfl_down(s, off);
    __shared__ float l[4];
    int lane = threadIdx.x & 63, wv = threadIdx.x >> 6;
    if (lane == 0) l[wv] = s;
    __syncthreads();
    if (threadIdx.x == 0) alpha[conv*CH + o] = (l[0]+l[1]+l[2]+l[3]) * (1.f/KKE);
}

// ---------------- pack activations: x -> (sign,mask) bit-planes, padded ----------------
// asign/amask layout: [n][hp][wp][8] u32 (zero-padded border).  Tb[p] = sum popc(mask).
__global__ void pack_x_kernel(const float* __restrict__ x,
                              uint32_t* __restrict__ asign, uint32_t* __restrict__ amask,
                              int* __restrict__ Tb) {
    int p = blockIdx.x*256 + threadIdx.x;
    if (p >= PADPIX) return;
    int n  = p / (HP*WP);
    int r  = p - n*(HP*WP);
    int hp = r / WP, wp = r - hp*WP;
    uint32_t sw[NWORDS], mw[NWORDS];
    int T = 0;
    if (hp >= 1 && hp <= HH && wp >= 1 && wp <= WW) {
        const float* xb = x + (size_t)n*CH*HWSZ + (hp-1)*WW + (wp-1);
        for (int wd = 0; wd < NWORDS; ++wd) {
            uint32_t sm = 0, mm = 0;
            for (int j = 0; j < 32; ++j) {
                float v = xb[(size_t)(wd*32 + j)*HWSZ];
                if (v > 0.f)  sm |= 1u << j;
                if (v != 0.f) mm |= 1u << j;
            }
            sw[wd] = sm; mw[wd] = mm;
            T += __popc(mm);
        }
    } else {
        for (int wd = 0; wd < NWORDS; ++wd) { sw[wd] = 0; mw[wd] = 0; }
    }
    uint4* as4 = (uint4*)(asign + (size_t)p*NWORDS);
    as4[0] = make_uint4(sw[0],sw[1],sw[2],sw[3]);
    as4[1] = make_uint4(sw[4],sw[5],sw[6],sw[7]);
    uint4* am4 = (uint4*)(amask + (size_t)p*NWORDS);
    am4[0] = make_uint4(mw[0],mw[1],mw[2],mw[3]);
    am4[1] = make_uint4(mw[4],mw[5],mw[6],mw[7]);
    Tb[p] = T;
}

// ---------------- pack sign(BN1(cnt)) the same way ----------------
__global__ void pack_s_kernel(const int16_t* __restrict__ cnt,
                              const float* __restrict__ ab,   // a = ab[0..255], b = ab[256..511]
                              uint32_t* __restrict__ asign, uint32_t* __restrict__ amask,
                              int* __restrict__ Tb) {
    int p = blockIdx.x*256 + threadIdx.x;
    if (p >= PADPIX) return;
    int n  = p / (HP*WP);
    int r  = p - n*(HP*WP);
    int hp = r / WP, wp = r - hp*WP;
    uint32_t sw[NWORDS], mw[NWORDS];
    int T = 0;
    if (hp >= 1 && hp <= HH && wp >= 1 && wp <= WW) {
        const int16_t* cb = cnt + (size_t)n*CH*HWSZ + (hp-1)*WW + (wp-1);
        for (int wd = 0; wd < NWORDS; ++wd) {
            uint32_t sm = 0, mm = 0;
            for (int j = 0; j < 32; ++j) {
                int cc = wd*32 + j;
                float v = fmaf(ab[cc], (float)cb[(size_t)cc*HWSZ], ab[CH + cc]);
                if (v > 0.f)  sm |= 1u << j;
                if (v != 0.f) mm |= 1u << j;
            }
            sw[wd] = sm; mw[wd] = mm;
            T += __popc(mm);
        }
    } else {
        for (int wd = 0; wd < NWORDS; ++wd) { sw[wd] = 0; mw[wd] = 0; }
    }
    uint4* as4 = (uint4*)(asign + (size_t)p*NWORDS);
    as4[0] = make_uint4(sw[0],sw[1],sw[2],sw[3]);
    as4[1] = make_uint4(sw[4],sw[5],sw[6],sw[7]);
    uint4* am4 = (uint4*)(amask + (size_t)p*NWORDS);
    am4[0] = make_uint4(mw[0],mw[1],mw[2],mw[3]);
    am4[1] = make_uint4(mw[4],mw[5],mw[6],mw[7]);
    Tb[p] = T;
}

// ---------------- binary 3x3 conv via xnor-popcount ----------------
// cnt(p,o) = 2 * sum_{tap,wd} popc(m & (s ^ wneg)) - sum_{tap,wd} popc(m)   (second term = base)
__global__ __launch_bounds__(256) void conv_kernel(
        const uint32_t* __restrict__ asign, const uint32_t* __restrict__ amask,
        const int* __restrict__ Tb,
        const uint32_t* __restrict__ wb, const uint32_t* __restrict__ wz,
        const uint32_t* __restrict__ wzany,
        int16_t* __restrict__ cnt_out) {
    int p = blockIdx.x*256 + threadIdx.x;          // NPIX = 392*256 exactly
    int n = p / HWSZ;
    int r = p - n*HWSZ;
    int h = r / WW, w = r - h*WW;
    int pbase = (n*HP + h)*WP + w;                 // padded top-left of 3x3 window

    int base = 0;
    #pragma unroll
    for (int dh = 0; dh < 3; ++dh)
        #pragma unroll
        for (int dw = 0; dw < 3; ++dw)
            base += Tb[pbase + dh*WP + dw];

    #pragma unroll 1
    for (int og = 0; og < 4; ++og) {               // 4 blocks of 16 output channels
        int o0 = blockIdx.y*64 + og*16;
        int acc[16];
        int corr[16];
        #pragma unroll
        for (int i = 0; i < 16; ++i) { acc[i] = 0; corr[i] = 0; }

        #pragma unroll 1
        for (int tap = 0; tap < NTAPS; ++tap) {
            size_t aoff = (size_t)(pbase + (tap/3)*WP + (tap%3))*NWORDS;
            uint4 s0 = *(const uint4*)(asign + aoff);
            uint4 s1 = *(const uint4*)(asign + aoff + 4);
            uint4 m0 = *(const uint4*)(amask + aoff);
            uint4 m1 = *(const uint4*)(amask + aoff + 4);
            const uint32_t* wrow = wb + ((size_t)tap*CH + o0)*NWORDS;   // uniform -> s_load
            #pragma unroll
            for (int oo = 0; oo < 16; ++oo) {
                const uint32_t* wr = wrow + oo*NWORDS;
                int a = 0;
                a += __popc(m0.x & (s0.x ^ wr[0]));
                a += __popc(m0.y & (s0.y ^ wr[1]));
                a += __popc(m0.z & (s0.z ^ wr[2]));
                a += __popc(m0.w & (s0.w ^ wr[3]));
                a += __popc(m1.x & (s1.x ^ wr[4]));
                a += __popc(m1.y & (s1.y ^ wr[5]));
                a += __popc(m1.z & (s1.z ^ wr[6]));
                a += __popc(m1.w & (s1.w ^ wr[7]));
                acc[oo] += a;
            }
            // exact handling of w==0 (sign(0)=0): nearly never taken, wave-uniform branch
            uint32_t anyz = wzany[tap*16 + (o0 >> 4)];
            if (anyz) {
                uint32_t sa[8] = {s0.x,s0.y,s0.z,s0.w,s1.x,s1.y,s1.z,s1.w};
                uint32_t ma[8] = {m0.x,m0.y,m0.z,m0.w,m1.x,m1.y,m1.z,m1.w};
                const uint32_t* wzrow = wz + ((size_t)tap*CH + o0)*NWORDS;
                #pragma unroll 1
                for (int oo = 0; oo < 16; ++oo) {
                    const uint32_t* zr = wzrow + oo*NWORDS;
                    int c = 0;
                    for (int wd2 = 0; wd2 < 8; ++wd2) {
                        uint32_t z = zr[wd2];
                        c += __popc(ma[wd2] &  sa[wd2] & z);
                        c -= __popc(ma[wd2] & ~sa[wd2] & z);
                    }
                    corr[oo] += c;
                }
            }
        }
        int16_t* co = cnt_out + ((size_t)n*CH + o0)*HWSZ + h*WW + w;
        #pragma unroll
        for (int oo = 0; oo < 16; ++oo)
            co[(size_t)oo*HWSZ] = (int16_t)(2*acc[oo] - base - corr[oo]);
    }
}

// ---------------- exact per-channel stats: sum cnt, sum cnt^2 ----------------
__global__ void stats_kernel(const int16_t* __restrict__ cnt, long long* __restrict__ sums) {
    int o = blockIdx.x;
    int chunk = blockIdx.y;                        // 8 chunks of 4 batch images
    int s1 = 0; long long s2 = 0;
    for (int nn = chunk*4; nn < chunk*4 + 4; ++nn) {
        const int16_t* pl = cnt + ((size_t)nn*CH + o)*HWSZ;
        for (int i = threadIdx.x; i < HWSZ; i += 256) {
            int v = pl[i];
            s1 += v;
            s2 += v*v;
        }
    }
    long long t1 = s1, t2 = s2;
    for (int off = 32; off; off >>= 1) { t1 += __shfl_down(t1, off); t2 += __shfl_down(t2, off); }
    __shared__ long long l1[4], l2[4];
    int lane = threadIdx.x & 63, wv = threadIdx.x >> 6;
    if (lane == 0) { l1[wv] = t1; l2[wv] = t2; }
    __syncthreads();
    if (threadIdx.x == 0) {
        long long a = l1[0]+l1[1]+l1[2]+l1[3];
        long long b = l2[0]+l2[1]+l2[2]+l2[3];
        atomicAdd((unsigned long long*)&sums[2*o],   (unsigned long long)a);
        atomicAdd((unsigned long long*)&sums[2*o+1], (unsigned long long)b);
    }
}

// ---------------- BN coefficients: BN(alpha*cnt) = a*cnt + b ----------------
__global__ void bncoef_kernel(const long long* __restrict__ sums,
                              const float* __restrict__ alpha,
                              const float* __restrict__ gamma, const float* __restrict__ beta,
                              float* __restrict__ ab) {
    int o = threadIdx.x;
    double S1 = (double)sums[2*o], S2 = (double)sums[2*o+1];
    double mean = S1 / NPIXD;
    double var  = S2 / NPIXD - mean*mean;
    double al   = (double)alpha[o];
    double rs   = 1.0 / sqrt(al*al*var + 1e-5);
    double a    = (double)gamma[o] * al * rs;
    ab[o]      = (float)a;
    ab[CH + o] = (float)((double)beta[o] - a*mean);
}

// ---------------- fused epilogue: out = a2*cnt2 + b2 + x ----------------
__global__ void final_kernel(const int16_t* __restrict__ cnt, const float* __restrict__ x,
                             const float* __restrict__ ab, float* __restrict__ out) {
    size_t t = (size_t)blockIdx.x*256 + threadIdx.x;
    size_t base = t*4;                              // HWSZ % 4 == 0 -> same channel for all 4
    int c = (int)((base / HWSZ) & 255);
    float a = ab[c], b = ab[CH + c];
    short4 cv = *(const short4*)(cnt + base);
    float4 xv = *(const float4*)(x + base);
    float4 ov;
    ov.x = fmaf(a, (float)cv.x, b) + xv.x;
    ov.y = fmaf(a, (float)cv.y, b) + xv.y;
    ov.z = fmaf(a, (float)cv.z, b) + xv.z;
    ov.w = fmaf(a, (float)cv.w, b) + xv.w;
    *(float4*)(out + base) = ov;
}

extern "C" void kernel_launch(void* const* d_in, const int* in_sizes, int n_in,
                              void* d_out, int out_size, void* d_ws, size_t ws_size,
                              hipStream_t stream) {
    const float* x  = (const float*)d_in[0];
    const float* w1 = (const float*)d_in[1];
    const float* g1 = (const float*)d_in[2];
    const float* b1 = (const float*)d_in[3];
    const float* w2 = (const float*)d_in[4];
    const float* g2 = (const float*)d_in[5];
    const float* b2 = (const float*)d_in[6];
    float* out = (float*)d_out;

    char* ws = (char*)d_ws;
    size_t off = 0;
    auto alloc = [&](size_t nbytes) { char* pp = ws + off; off = (off + nbytes + 255) & ~(size_t)255; return pp; };
    uint32_t* asign = (uint32_t*)alloc((size_t)PADPIX*NWORDS*4);   // 3.44 MB
    uint32_t* amask = (uint32_t*)alloc((size_t)PADPIX*NWORDS*4);   // 3.44 MB
    int*      Tb    = (int*)alloc((size_t)PADPIX*4);               // 0.43 MB
    int16_t*  cnt   = (int16_t*)alloc((size_t)NPIX*CH*2);          // 51.4 MB (reused by both convs)
    uint32_t* wb    = (uint32_t*)alloc((size_t)2*NTAPS*CH*NWORDS*4);
    uint32_t* wzb   = (uint32_t*)alloc((size_t)2*NTAPS*CH*NWORDS*4);
    uint32_t* wzany = (uint32_t*)alloc((size_t)2*NTAPS*16*4);
    float*    alpha = (float*)alloc((size_t)2*CH*4);
    long long* sums = (long long*)alloc((size_t)2*CH*2*8);
    float*    ab    = (float*)alloc((size_t)2*2*CH*4);             // [a1,b1 | a2,b2]

    init_kernel<<<4, 256, 0, stream>>>(sums, wzany);
    packw_kernel<<<dim3(72, 2), 256, 0, stream>>>(w1, w2, wb, wzb, wzany);
    alpha_kernel<<<dim3(CH, 2), 256, 0, stream>>>(w1, w2, alpha);
    pack_x_kernel<<<(PADPIX + 255)/256, 256, 0, stream>>>(x, asign, amask, Tb);

    conv_kernel<<<dim3(NPIX/256, 4), 256, 0, stream>>>(asign, amask, Tb, wb, wzb, wzany, cnt);
    stats_kernel<<<dim3(CH, 8), 256, 0, stream>>>(cnt, sums);
    bncoef_kernel<<<1, CH, 0, stream>>>(sums, alpha, g1, b1, ab);

    pack_s_kernel<<<(PADPIX + 255)/256, 256, 0, stream>>>(cnt, ab, asign, amask, Tb);
    conv_kernel<<<dim3(NPIX/256, 4), 256, 0, stream>>>(asign, amask, Tb,
            wb + (size_t)NTAPS*CH*NWORDS, wzb + (size_t)NTAPS*CH*NWORDS, wzany + NTAPS*16, cnt);
    stats_kernel<<<dim3(CH, 8), 256, 0, stream>>>(cnt, sums + 2*CH);
    bncoef_kernel<<<1, CH, 0, stream>>>(sums + 2*CH, alpha + CH, g2, b2, ab + 2*CH);

    final_kernel<<<NPIX*CH/4/256, 256, 0, stream>>>(cnt, x, ab + 2*CH, out);
}

// Round 2
// 450.993 us; speedup vs baseline: 1.2170x; 1.2170x over previous
//
#include <hip/hip_runtime.h>
#include <stdint.h>

// Problem constants (N,C,H,W fixed by the reference)
#define NB 32
#define CH 256
#define HH 56
#define WW 56
#define HWSZ (HH*WW)            // 3136
#define NPIX (NB*HWSZ)          // 100352 = 392*256 exactly
#define HP 58
#define WP 58
#define PADPIX (NB*HP*WP)       // 107648
#define NWORDS 8                // 256 channels / 32 bits
#define NTAPS 9
#define KKE (CH*NTAPS)          // 2304
#define NPIXD 100352.0

// ---------------- init: zero accumulators/flags ----------------
__global__ void init_kernel(long long* __restrict__ sums, uint32_t* __restrict__ wzany) {
    int t = blockIdx.x*256 + threadIdx.x;
    if (t < 1024) sums[t] = 0;     // 2 convs x 256 ch x {sum,sumsq}
    if (t < 2)    wzany[t] = 0;    // per-conv "any exactly-zero weight" flag
}

// ---------------- pack weights into bit-words ----------------
// wb[conv][tap][o][wd]: bit j = 1 iff w(o, 32*wd+j, tap) < 0
// wz: bit = 1 iff w == 0 exactly (never in practice; exact cold-path fix)
__global__ void packw_kernel(const float* __restrict__ w1, const float* __restrict__ w2,
                             uint32_t* __restrict__ wb, uint32_t* __restrict__ wz,
                             uint32_t* __restrict__ wzany) {
    int t = blockIdx.x*256 + threadIdx.x;          // 72 blocks -> 18432 = 9*256*8
    if (t >= NTAPS*CH*NWORDS) return;
    int conv = blockIdx.y;
    const float* w = conv ? w2 : w1;
    int wd  = t & 7;
    int o   = (t >> 3) & 255;
    int tap = t >> 11;
    uint32_t nb = 0, zb = 0;
    for (int j = 0; j < 32; ++j) {
        float v = w[(size_t)(o*CH + wd*32 + j)*NTAPS + tap];
        if (v < 0.f)  nb |= 1u << j;
        if (v == 0.f) zb |= 1u << j;
    }
    size_t base = (size_t)conv*NTAPS*CH*NWORDS;
    wb[base + t] = nb;             // t == (tap*256 + o)*8 + wd
    wz[base + t] = zb;
    if (zb) atomicOr(&wzany[conv], 1u);
}

// ---------------- border-correction table ----------------
// case id = ct*3+cl, ct/cl in {0=interior,1=low edge,2=high edge}
// corrtab[conv][case][o] = sum over invalid taps of (2*popc(wneg_row) - 256)
__global__ void corrtab_kernel(const uint32_t* __restrict__ wb, int* __restrict__ corrtab) {
    int o = threadIdx.x;       // 256
    int conv = blockIdx.x;     // 2
    const uint32_t* w = wb + (size_t)conv*NTAPS*CH*NWORDS;
    int wpc[9];
    #pragma unroll
    for (int tap = 0; tap < 9; ++tap) {
        int s = 0;
        #pragma unroll
        for (int wd = 0; wd < 8; ++wd) s += __popc(w[(tap*CH + o)*NWORDS + wd]);
        wpc[tap] = 2*s - 256;
    }
    #pragma unroll
    for (int ct = 0; ct < 3; ++ct)
    #pragma unroll
    for (int cl = 0; cl < 3; ++cl) {
        int s = 0;
        #pragma unroll
        for (int tap = 0; tap < 9; ++tap) {
            int dh = tap/3, dw = tap%3;
            bool inv = (ct==1 && dh==0) || (ct==2 && dh==2) ||
                       (cl==1 && dw==0) || (cl==2 && dw==2);
            if (inv) s += wpc[tap];
        }
        corrtab[(size_t)conv*9*CH + (ct*3+cl)*CH + o] = s;
    }
}

// ---------------- alpha[o] = mean |w| over (I,3,3) ----------------
__global__ void alpha_kernel(const float* __restrict__ w1, const float* __restrict__ w2,
                             float* __restrict__ alpha) {
    int o = blockIdx.x; int conv = blockIdx.y;
    const float* w = conv ? w2 : w1;
    float s = 0.f;
    for (int i = threadIdx.x; i < KKE; i += 256) s += fabsf(w[(size_t)o*KKE + i]);
    for (int off = 32; off; off >>= 1) s += __shfl_down(s, off);
    __shared__ float l[4];
    int lane = threadIdx.x & 63, wv = threadIdx.x >> 6;
    if (lane == 0) l[wv] = s;
    __syncthreads();
    if (threadIdx.x == 0) alpha[conv*CH + o] = (l[0]+l[1]+l[2]+l[3]) * (1.f/KKE);
}

// ---------------- pack activations: x -> sign bit-plane, padded ----------------
__global__ void pack_x_kernel(const float* __restrict__ x, uint32_t* __restrict__ asign) {
    int p = blockIdx.x*256 + threadIdx.x;
    if (p >= PADPIX) return;
    int n  = p / (HP*WP);
    int r  = p - n*(HP*WP);
    int hp = r / WP, wp = r - hp*WP;
    uint32_t sw[NWORDS];
    if (hp >= 1 && hp <= HH && wp >= 1 && wp <= WW) {
        const float* xb = x + (size_t)n*CH*HWSZ + (hp-1)*WW + (wp-1);
        #pragma unroll
        for (int wd = 0; wd < NWORDS; ++wd) {
            uint32_t sm = 0;
            #pragma unroll
            for (int j = 0; j < 32; ++j) {
                float v = xb[(size_t)(wd*32 + j)*HWSZ];
                sm |= (v > 0.f) ? (1u << j) : 0u;
            }
            sw[wd] = sm;
        }
    } else {
        #pragma unroll
        for (int wd = 0; wd < NWORDS; ++wd) sw[wd] = 0;
    }
    uint4* d = (uint4*)(asign + (size_t)p*NWORDS);
    d[0] = make_uint4(sw[0],sw[1],sw[2],sw[3]);
    d[1] = make_uint4(sw[4],sw[5],sw[6],sw[7]);
}

// ---------------- pack sign(BN1(cnt)) the same way ----------------
__global__ void pack_s_kernel(const int16_t* __restrict__ cnt,
                              const float* __restrict__ ab,   // a=ab[0..255], b=ab[256..511]
                              uint32_t* __restrict__ asign) {
    int p = blockIdx.x*256 + threadIdx.x;
    if (p >= PADPIX) return;
    int n  = p / (HP*WP);
    int r  = p - n*(HP*WP);
    int hp = r / WP, wp = r - hp*WP;
    uint32_t sw[NWORDS];
    if (hp >= 1 && hp <= HH && wp >= 1 && wp <= WW) {
        const int16_t* cb = cnt + (size_t)n*CH*HWSZ + (hp-1)*WW + (wp-1);
        #pragma unroll
        for (int wd = 0; wd < NWORDS; ++wd) {
            uint32_t sm = 0;
            #pragma unroll
            for (int j = 0; j < 32; ++j) {
                int cc = wd*32 + j;
                float v = fmaf(ab[cc], (float)cb[(size_t)cc*HWSZ], ab[CH + cc]);
                sm |= (v > 0.f) ? (1u << j) : 0u;
            }
            sw[wd] = sm;
        }
    } else {
        #pragma unroll
        for (int wd = 0; wd < NWORDS; ++wd) sw[wd] = 0;
    }
    uint4* d = (uint4*)(asign + (size_t)p*NWORDS);
    d[0] = make_uint4(sw[0],sw[1],sw[2],sw[3]);
    d[1] = make_uint4(sw[4],sw[5],sw[6],sw[7]);
}

// ---------------- binary 3x3 conv via xnor-popcount (sign-only) ----------------
// per tap: cnt contribution = 2*popc(s ^ wneg) - 256; pad pixels have s=0,
// their (wrong) contribution is removed exactly via corrtab[case][o].
__global__ __launch_bounds__(256, 4) void conv_kernel(
        const uint32_t* __restrict__ asign,
        const uint32_t* __restrict__ wb, const uint32_t* __restrict__ wz,
        const uint32_t* __restrict__ anyz,
        const int* __restrict__ corrtab,          // [9][256] for this conv
        int16_t* __restrict__ cnt_out) {
    __shared__ uint32_t lw[NTAPS*64*NWORDS];      // 18 KB weights for 64 outputs
    __shared__ int lct[9*64];                     // 2.25 KB border corrections
    int o0 = blockIdx.y * 64;
    for (int i = threadIdx.x; i < NTAPS*64*NWORDS; i += 256) {
        int tap = i >> 9, rem = i & 511;          // rem = oo*8+wd
        lw[i] = wb[tap*(CH*NWORDS) + o0*NWORDS + rem];
    }
    for (int i = threadIdx.x; i < 9*64; i += 256) {
        int cse = i >> 6, oo = i & 63;
        lct[i] = corrtab[cse*CH + o0 + oo];
    }
    __syncthreads();

    int p = blockIdx.x*256 + threadIdx.x;         // NPIX = 392*256 exactly
    int n = p / HWSZ;
    int r = p - n*HWSZ;
    int h = r / WW, w = r - h*WW;
    int pbase = (n*HP + h)*WP + w;                // padded top-left of 3x3 window

    int acc[64];
    #pragma unroll
    for (int i = 0; i < 64; ++i) acc[i] = 0;

    #pragma unroll 1
    for (int tap = 0; tap < NTAPS; ++tap) {
        const uint4* a4 = (const uint4*)(asign + (size_t)(pbase + (tap/3)*WP + (tap%3))*NWORDS);
        uint4 s0 = a4[0], s1 = a4[1];
        const uint32_t* lwt = lw + tap*512;
        #pragma unroll
        for (int oo = 0; oo < 64; ++oo) {
            const uint4* w4 = (const uint4*)(lwt + oo*8);
            uint4 w0 = w4[0], w1 = w4[1];
            int a;
            a  = __popc(s0.x ^ w0.x);
            a += __popc(s0.y ^ w0.y);
            a += __popc(s0.z ^ w0.z);
            a += __popc(s0.w ^ w0.w);
            a += __popc(s1.x ^ w1.x);
            a += __popc(s1.y ^ w1.y);
            a += __popc(s1.z ^ w1.z);
            a += __popc(s1.w ^ w1.w);
            acc[oo] += a << 1;                    // v_lshl_add
        }
    }

    // border fixup + store: cnt = acc - 2304 - corrtab[case]
    int ct = (h == 0) ? 1 : ((h == HH-1) ? 2 : 0);
    int cl = (w == 0) ? 1 : ((w == WW-1) ? 2 : 0);
    const int* ctab = lct + (ct*3 + cl)*64;
    int16_t* co = cnt_out + ((size_t)n*CH + o0)*HWSZ + h*WW + w;
    #pragma unroll
    for (int oo = 0; oo < 64; ++oo)
        co[(size_t)oo*HWSZ] = (int16_t)(acc[oo] - KKE - ctab[oo]);

    // exact w==0 correction (cold: essentially never taken; rolled, patches memory)
    if (*anyz) {
        #pragma unroll 1
        for (int tap = 0; tap < NTAPS; ++tap) {
            int dh = tap/3, dw = tap%3;
            bool valid = ((unsigned)(h-1+dh) < (unsigned)HH) & ((unsigned)(w-1+dw) < (unsigned)WW);
            const uint32_t* sa = asign + (size_t)(pbase + dh*WP + dw)*NWORDS;
            #pragma unroll 1
            for (int o = 0; o < 64; ++o) {
                const uint32_t* zr = wz + (size_t)(tap*CH + o0 + o)*NWORDS;
                int c = 0;
                #pragma unroll 1
                for (int wd = 0; wd < NWORDS; ++wd) {
                    uint32_t z = zr[wd];
                    if (z) { uint32_t s = sa[wd]; c += __popc(s & z) - __popc(~s & z); }
                }
                if (valid && c) {
                    int16_t* cp = cnt_out + ((size_t)n*CH + o0 + o)*HWSZ + h*WW + w;
                    *cp = (int16_t)(*cp - c);
                }
            }
        }
    }
}

// ---------------- exact per-channel stats: sum cnt, sum cnt^2 ----------------
__global__ void stats_kernel(const int16_t* __restrict__ cnt, long long* __restrict__ sums) {
    int o = blockIdx.x;
    int chunk = blockIdx.y;                        // 8 chunks of 4 batch images
    int s1 = 0; long long s2 = 0;
    for (int nn = chunk*4; nn < chunk*4 + 4; ++nn) {
        const int16_t* pl = cnt + ((size_t)nn*CH + o)*HWSZ;
        for (int i = threadIdx.x; i < HWSZ; i += 256) {
            int v = pl[i];
            s1 += v;
            s2 += v*v;
        }
    }
    long long t1 = s1, t2 = s2;
    for (int off = 32; off; off >>= 1) { t1 += __shfl_down(t1, off); t2 += __shfl_down(t2, off); }
    __shared__ long long l1[4], l2[4];
    int lane = threadIdx.x & 63, wv = threadIdx.x >> 6;
    if (lane == 0) { l1[wv] = t1; l2[wv] = t2; }
    __syncthreads();
    if (threadIdx.x == 0) {
        long long a = l1[0]+l1[1]+l1[2]+l1[3];
        long long b = l2[0]+l2[1]+l2[2]+l2[3];
        atomicAdd((unsigned long long*)&sums[2*o],   (unsigned long long)a);
        atomicAdd((unsigned long long*)&sums[2*o+1], (unsigned long long)b);
    }
}

// ---------------- BN coefficients: BN(alpha*cnt) = a*cnt + b ----------------
__global__ void bncoef_kernel(const long long* __restrict__ sums,
                              const float* __restrict__ alpha,
                              const float* __restrict__ gamma, const float* __restrict__ beta,
                              float* __restrict__ ab) {
    int o = threadIdx.x;
    double S1 = (double)sums[2*o], S2 = (double)sums[2*o+1];
    double mean = S1 / NPIXD;
    double var  = S2 / NPIXD - mean*mean;
    double al   = (double)alpha[o];
    double rs   = 1.0 / sqrt(al*al*var + 1e-5);
    double a    = (double)gamma[o] * al * rs;
    ab[o]      = (float)a;
    ab[CH + o] = (float)((double)beta[o] - a*mean);
}

// ---------------- fused epilogue: out = a2*cnt2 + b2 + x ----------------
__global__ void final_kernel(const int16_t* __restrict__ cnt, const float* __restrict__ x,
                             const float* __restrict__ ab, float* __restrict__ out) {
    size_t t = (size_t)blockIdx.x*256 + threadIdx.x;
    size_t base = t*4;                              // HWSZ % 4 == 0 -> same channel for all 4
    int c = (int)((base / HWSZ) & 255);
    float a = ab[c], b = ab[CH + c];
    short4 cv = *(const short4*)(cnt + base);
    float4 xv = *(const float4*)(x + base);
    float4 ov;
    ov.x = fmaf(a, (float)cv.x, b) + xv.x;
    ov.y = fmaf(a, (float)cv.y, b) + xv.y;
    ov.z = fmaf(a, (float)cv.z, b) + xv.z;
    ov.w = fmaf(a, (float)cv.w, b) + xv.w;
    *(float4*)(out + base) = ov;
}

extern "C" void kernel_launch(void* const* d_in, const int* in_sizes, int n_in,
                              void* d_out, int out_size, void* d_ws, size_t ws_size,
                              hipStream_t stream) {
    const float* x  = (const float*)d_in[0];
    const float* w1 = (const float*)d_in[1];
    const float* g1 = (const float*)d_in[2];
    const float* b1 = (const float*)d_in[3];
    const float* w2 = (const float*)d_in[4];
    const float* g2 = (const float*)d_in[5];
    const float* b2 = (const float*)d_in[6];
    float* out = (float*)d_out;

    char* ws = (char*)d_ws;
    size_t off = 0;
    auto alloc = [&](size_t nbytes) { char* pp = ws + off; off = (off + nbytes + 255) & ~(size_t)255; return pp; };
    uint32_t* asign = (uint32_t*)alloc((size_t)PADPIX*NWORDS*4);   // 3.44 MB
    int16_t*  cnt   = (int16_t*)alloc((size_t)NPIX*CH*2);          // 51.4 MB (reused by both convs)
    uint32_t* wb    = (uint32_t*)alloc((size_t)2*NTAPS*CH*NWORDS*4);
    uint32_t* wzb   = (uint32_t*)alloc((size_t)2*NTAPS*CH*NWORDS*4);
    uint32_t* wzany = (uint32_t*)alloc((size_t)2*4);
    int*      ctab  = (int*)alloc((size_t)2*9*CH*4);               // border corrections
    float*    alpha = (float*)alloc((size_t)2*CH*4);
    long long* sums = (long long*)alloc((size_t)2*CH*2*8);
    float*    ab    = (float*)alloc((size_t)2*2*CH*4);             // [a1,b1 | a2,b2]

    init_kernel<<<4, 256, 0, stream>>>(sums, wzany);
    packw_kernel<<<dim3(72, 2), 256, 0, stream>>>(w1, w2, wb, wzb, wzany);
    corrtab_kernel<<<2, 256, 0, stream>>>(wb, ctab);
    alpha_kernel<<<dim3(CH, 2), 256, 0, stream>>>(w1, w2, alpha);
    pack_x_kernel<<<(PADPIX + 255)/256, 256, 0, stream>>>(x, asign);

    conv_kernel<<<dim3(NPIX/256, 4), 256, 0, stream>>>(asign, wb, wzb, wzany, ctab, cnt);
    stats_kernel<<<dim3(CH, 8), 256, 0, stream>>>(cnt, sums);
    bncoef_kernel<<<1, CH, 0, stream>>>(sums, alpha, g1, b1, ab);

    pack_s_kernel<<<(PADPIX + 255)/256, 256, 0, stream>>>(cnt, ab, asign);
    conv_kernel<<<dim3(NPIX/256, 4), 256, 0, stream>>>(asign,
            wb + (size_t)NTAPS*CH*NWORDS, wzb + (size_t)NTAPS*CH*NWORDS, wzany + 1,
            ctab + 9*CH, cnt);
    stats_kernel<<<dim3(CH, 8), 256, 0, stream>>>(cnt, sums + 2*CH);
    bncoef_kernel<<<1, CH, 0, stream>>>(sums + 2*CH, alpha + CH, g2, b2, ab + 2*CH);

    final_kernel<<<NPIX*CH/4/256, 256, 0, stream>>>(cnt, x, ab + 2*CH, out);
}

// Round 3
// 324.653 us; speedup vs baseline: 1.6906x; 1.3892x over previous
//
#include <hip/hip_runtime.h>
#include <stdint.h>

// Problem constants (N,C,H,W fixed by the reference)
#define NB 32
#define CH 256
#define HH 56
#define WW 56
#define HWSZ (HH*WW)            // 3136
#define NPIX (NB*HWSZ)          // 100352
#define HP 58
#define WP 58
#define PADPIX (NB*HP*WP)       // 107648
#define NTAPS 9
#define KKE (CH*NTAPS)          // 2304
#define NPIXD 100352.0
#define WQ_CONV (NTAPS*8*8*64*16)   // 589824 bytes of prepacked weights per conv

typedef int int4v  __attribute__((ext_vector_type(4)));
typedef int int16v __attribute__((ext_vector_type(16)));

// ---------------- init: zero stats accumulators ----------------
__global__ void init_kernel(long long* __restrict__ sums) {
    int t = blockIdx.x*256 + threadIdx.x;
    if (t < 1024) sums[t] = 0;     // 2 convs x 256 ch x {sum,sumsq}
}

// ---------------- prepack weights into MFMA B-fragment layout ----------------
// wq[conv][tap][ks][nb][lane][16B]: byte b of lane l = sign(w[o][cin][tap])
// with o = nb*32 + (l&31), cin = ks*32 + (l>>5)*16 + b.  (B-frag: col=l&31, k-half=l>>5)
__global__ void wqpack_kernel(const float* __restrict__ w1, const float* __restrict__ w2,
                              int8_t* __restrict__ wq) {
    int t = blockIdx.x*256 + threadIdx.x;     // 144 blocks -> 36864 threads
    int conv = blockIdx.y;
    const float* w = conv ? w2 : w1;
    int lane = t & 63;
    int g = t >> 6;                 // (tap*8+ks)*8+nb
    int nb = g & 7, h = g >> 3;
    int ks = h & 7, tap = h >> 3;
    int o = nb*32 + (lane & 31);
    int cin0 = ks*32 + (lane >> 5)*16;
    int wd[4];
    #pragma unroll
    for (int q = 0; q < 4; ++q) {
        int wv = 0;
        #pragma unroll
        for (int j = 0; j < 4; ++j) {
            float v = w[(size_t)(o*CH + cin0 + q*4 + j)*NTAPS + tap];
            int s = (v > 0.f) ? 1 : ((v < 0.f) ? -1 : 0);
            wv |= (s & 0xff) << (8*j);
        }
        wd[q] = wv;
    }
    *(int4v*)(wq + (size_t)conv*WQ_CONV + (size_t)t*16) = (int4v){wd[0], wd[1], wd[2], wd[3]};
}

// ---------------- alpha[o] = mean |w| over (I,3,3) ----------------
__global__ void alpha_kernel(const float* __restrict__ w1, const float* __restrict__ w2,
                             float* __restrict__ alpha) {
    int o = blockIdx.x; int conv = blockIdx.y;
    const float* w = conv ? w2 : w1;
    float s = 0.f;
    for (int i = threadIdx.x; i < KKE; i += 256) s += fabsf(w[(size_t)o*KKE + i]);
    for (int off = 32; off; off >>= 1) s += __shfl_down(s, off);
    __shared__ float l[4];
    int lane = threadIdx.x & 63, wv = threadIdx.x >> 6;
    if (lane == 0) l[wv] = s;
    __syncthreads();
    if (threadIdx.x == 0) alpha[conv*CH + o] = (l[0]+l[1]+l[2]+l[3]) * (1.f/KKE);
}

// ---------------- pack activations: x -> int8 sign, padded, ch-contiguous ----------------
// apad[n][58][58][256] int8; border = 0.
__global__ void pack_x_kernel(const float* __restrict__ x, int8_t* __restrict__ apad) {
    int p = blockIdx.x*256 + threadIdx.x;
    if (p >= PADPIX) return;
    int n  = p / (HP*WP);
    int r  = p - n*(HP*WP);
    int hp = r / WP, wp = r - hp*WP;
    int4v* dst = (int4v*)(apad + (size_t)p*CH);
    if (hp >= 1 && hp <= HH && wp >= 1 && wp <= WW) {
        const float* xb = x + (size_t)n*CH*HWSZ + (hp-1)*WW + (wp-1);
        #pragma unroll 2
        for (int c16 = 0; c16 < 16; ++c16) {
            int wd[4];
            #pragma unroll
            for (int q = 0; q < 4; ++q) {
                int wv = 0;
                #pragma unroll
                for (int j = 0; j < 4; ++j) {
                    float v = xb[(size_t)(c16*16 + q*4 + j)*HWSZ];
                    int s = (v > 0.f) ? 1 : ((v < 0.f) ? -1 : 0);
                    wv |= (s & 0xff) << (8*j);
                }
                wd[q] = wv;
            }
            dst[c16] = (int4v){wd[0], wd[1], wd[2], wd[3]};
        }
    } else {
        int4v z = {0,0,0,0};
        #pragma unroll
        for (int c16 = 0; c16 < 16; ++c16) dst[c16] = z;
    }
}

// ---------------- pack sign(BN1(cnt)) -> int8, padded ----------------
__global__ void pack_s_kernel(const int16_t* __restrict__ cnt,
                              const float* __restrict__ ab,   // a=ab[0..255], b=ab[256..511]
                              int8_t* __restrict__ apad) {
    int p = blockIdx.x*256 + threadIdx.x;
    if (p >= PADPIX) return;
    int n  = p / (HP*WP);
    int r  = p - n*(HP*WP);
    int hp = r / WP, wp = r - hp*WP;
    int4v* dst = (int4v*)(apad + (size_t)p*CH);
    if (hp >= 1 && hp <= HH && wp >= 1 && wp <= WW) {
        const int4v* cb = (const int4v*)(cnt + ((size_t)n*HWSZ + (hp-1)*WW + (wp-1))*CH);
        #pragma unroll 2
        for (int c16 = 0; c16 < 16; ++c16) {
            int4v u0 = cb[c16*2], u1 = cb[c16*2+1];
            int wd[4];
            #pragma unroll
            for (int q = 0; q < 4; ++q) {
                int wv = 0;
                #pragma unroll
                for (int j = 0; j < 4; ++j) {
                    int e = q*4 + j;                       // 0..15 within this 16-ch group
                    int word = (e < 8) ? u0[e >> 1] : u1[(e-8) >> 1];
                    int sval = (e & 1) ? (word >> 16) : ((word << 16) >> 16);
                    int ch = c16*16 + e;
                    float v = fmaf(ab[ch], (float)sval, ab[CH + ch]);
                    int s = (v > 0.f) ? 1 : ((v < 0.f) ? -1 : 0);
                    wv |= (s & 0xff) << (8*j);
                }
                wd[q] = wv;
            }
            dst[c16] = (int4v){wd[0], wd[1], wd[2], wd[3]};
        }
    } else {
        int4v z = {0,0,0,0};
        #pragma unroll
        for (int c16 = 0; c16 < 16; ++c16) dst[c16] = z;
    }
}

// ---------------- int8 MFMA implicit-GEMM 3x3 conv ----------------
// wg = {2 images} x 8x8 pixels x 256 outs.  M=128 (4 subtiles), N=256 (8 nb), K=2304.
__global__ __launch_bounds__(256, 2) void conv_kernel(
        const int8_t* __restrict__ apad, const int8_t* __restrict__ wq,
        int16_t* __restrict__ cnt) {
    __shared__ int4v halo4[200*16];               // 2 images x 10x10 halo x 256ch, swizzled
    int8_t* halo = (int8_t*)halo4;
    int b = blockIdx.x;                           // 784 = 16 image-pairs x 49 tiles
    int tile = b % 49, npair = b / 49;
    int ty = tile / 7, tx = tile % 7;
    int n0 = npair * 2;
    int t = threadIdx.x;

    // stage halo: 200 pixels x 256B, XOR-swizzled within each 256B row
    #pragma unroll 1
    for (int j = 0; j < 13; ++j) {
        int idx = t + j*256;
        if (idx < 3200) {
            int pix = idx >> 4, c16 = idx & 15;
            int img = (pix >= 100) ? 1 : 0;
            int hp = pix - img*100;
            int dr = hp / 10, dc = hp - dr*10;
            const int4v* src = (const int4v*)(apad +
                ((size_t)(((n0+img)*HP + ty*8+dr)*WP + tx*8+dc))*CH + c16*16);
            *(int4v*)&halo[pix*256 + ((c16 ^ (pix & 15)) << 4)] = *src;
        }
    }
    __syncthreads();

    int lane = t & 63, wv = t >> 6;
    int kh = lane >> 5, lr = lane & 31;
    int r0 = lr >> 3, c0 = lr & 7;
    int hb0 = r0*10 + c0;            // img0, pixels 0..31
    int hb1 = (r0+4)*10 + c0;        // img0, pixels 32..63
    int hb2 = 100 + hb0;             // img1
    int hb3 = 100 + hb1;

    const int8_t* wp0 = wq + (size_t)(wv*2)*1024 + lane*16;
    const int8_t* wp1 = wp0 + 1024;

    int16v acc00, acc01, acc10, acc11, acc20, acc21, acc30, acc31;
    #pragma unroll
    for (int i = 0; i < 16; ++i) {
        acc00[i]=0; acc01[i]=0; acc10[i]=0; acc11[i]=0;
        acc20[i]=0; acc21[i]=0; acc30[i]=0; acc31[i]=0;
    }

#define LOADS(IT, A0,A1,A2,A3,B0,B1) do { \
        int tap_ = (IT) >> 3, ks_ = (IT) & 7; \
        int dh_ = tap_ / 3; \
        int toff_ = dh_*10 + (tap_ - dh_*3); \
        int kk_ = (ks_ << 1) | kh; \
        int hp_; \
        hp_ = hb0 + toff_; A0 = *(const int4v*)&halo[hp_*256 + ((kk_ ^ (hp_&15))<<4)]; \
        hp_ = hb1 + toff_; A1 = *(const int4v*)&halo[hp_*256 + ((kk_ ^ (hp_&15))<<4)]; \
        hp_ = hb2 + toff_; A2 = *(const int4v*)&halo[hp_*256 + ((kk_ ^ (hp_&15))<<4)]; \
        hp_ = hb3 + toff_; A3 = *(const int4v*)&halo[hp_*256 + ((kk_ ^ (hp_&15))<<4)]; \
        B0 = *(const int4v*)(wp0 + (size_t)(IT)*8192); \
        B1 = *(const int4v*)(wp1 + (size_t)(IT)*8192); \
    } while (0)

    int4v a0,a1,a2,a3,b0,b1, na0,na1,na2,na3,nb0,nb1;
    LOADS(0, a0,a1,a2,a3,b0,b1);
    #pragma unroll 2
    for (int it = 0; it < 72; ++it) {             // 9 taps x 8 k-steps
        int itn = (it + 1 < 72) ? it + 1 : 71;
        LOADS(itn, na0,na1,na2,na3,nb0,nb1);
        acc00 = __builtin_amdgcn_mfma_i32_32x32x32_i8(a0, b0, acc00, 0,0,0);
        acc01 = __builtin_amdgcn_mfma_i32_32x32x32_i8(a0, b1, acc01, 0,0,0);
        acc10 = __builtin_amdgcn_mfma_i32_32x32x32_i8(a1, b0, acc10, 0,0,0);
        acc11 = __builtin_amdgcn_mfma_i32_32x32x32_i8(a1, b1, acc11, 0,0,0);
        acc20 = __builtin_amdgcn_mfma_i32_32x32x32_i8(a2, b0, acc20, 0,0,0);
        acc21 = __builtin_amdgcn_mfma_i32_32x32x32_i8(a2, b1, acc21, 0,0,0);
        acc30 = __builtin_amdgcn_mfma_i32_32x32x32_i8(a3, b0, acc30, 0,0,0);
        acc31 = __builtin_amdgcn_mfma_i32_32x32x32_i8(a3, b1, acc31, 0,0,0);
        a0=na0; a1=na1; a2=na2; a3=na3; b0=nb0; b1=nb1;
    }
#undef LOADS

    // epilogue: C layout col=lane&31, row=(reg&3)+8*(reg>>2)+4*(lane>>5)
#define STOREACC(ACC, M, J) do { \
        int ch_ = (wv*2 + (J))*32 + lr; \
        int img_ = (M) >> 1; \
        _Pragma("unroll") \
        for (int reg = 0; reg < 16; ++reg) { \
            int row_ = (reg & 3) + 8*(reg >> 2) + 4*kh; \
            int pm_ = ((M) & 1)*32 + row_; \
            int rr_ = pm_ >> 3, cc_ = pm_ & 7; \
            cnt[(size_t)(((n0+img_)*HH + ty*8 + rr_)*WW + tx*8 + cc_)*CH + ch_] = (int16_t)ACC[reg]; \
        } \
    } while (0)

    STOREACC(acc00, 0, 0); STOREACC(acc01, 0, 1);
    STOREACC(acc10, 1, 0); STOREACC(acc11, 1, 1);
    STOREACC(acc20, 2, 0); STOREACC(acc21, 2, 1);
    STOREACC(acc30, 3, 0); STOREACC(acc31, 3, 1);
#undef STOREACC
}

// ---------------- exact per-channel stats over [pix][ch] layout ----------------
__global__ void stats_kernel(const int16_t* __restrict__ cnt, long long* __restrict__ sums) {
    int t = threadIdx.x;                          // channel
    size_t base = (size_t)blockIdx.x * 256;       // pixel base (392 blocks)
    int s1 = 0, s2 = 0;
    #pragma unroll 4
    for (int i = 0; i < 256; ++i) {
        int v = (int)cnt[(base + i)*CH + t];
        s1 += v; s2 += v*v;                       // max 256*2304^2 = 1.36e9 < 2^31
    }
    atomicAdd((unsigned long long*)&sums[2*t],   (unsigned long long)(long long)s1);
    atomicAdd((unsigned long long*)&sums[2*t+1], (unsigned long long)(long long)s2);
}

// ---------------- BN coefficients: BN(alpha*cnt) = a*cnt + b ----------------
__global__ void bncoef_kernel(const long long* __restrict__ sums,
                              const float* __restrict__ alpha,
                              const float* __restrict__ gamma, const float* __restrict__ beta,
                              float* __restrict__ ab) {
    int o = threadIdx.x;
    double S1 = (double)sums[2*o], S2 = (double)sums[2*o+1];
    double mean = S1 / NPIXD;
    double var  = S2 / NPIXD - mean*mean;
    double al   = (double)alpha[o];
    double rs   = 1.0 / sqrt(al*al*var + 1e-5);
    double a    = (double)gamma[o] * al * rs;
    ab[o]      = (float)a;
    ab[CH + o] = (float)((double)beta[o] - a*mean);
}

// ---------------- fused epilogue: out = a2*cnt2 + b2 + x  (LDS transpose) ----------------
__global__ __launch_bounds__(256) void final_kernel(const int16_t* __restrict__ cnt,
        const float* __restrict__ x, const float* __restrict__ ab, float* __restrict__ out) {
    __shared__ int4v lsd4[64*32];                 // 64 pixels x 512B, swizzled
    int8_t* lb = (int8_t*)lsd4;
    int b = blockIdx.x;                           // 1568 = 32 n x 49 tiles
    int n = b / 49, tile = b - n*49;
    int p0 = tile * 64;
    int t = threadIdx.x;
    const int4v* src = (const int4v*)(cnt + ((size_t)n*HWSZ + p0)*CH);
    #pragma unroll
    for (int j = 0; j < 8; ++j) {
        int c = t + j*256;                        // 2048 16B-chunks
        int pix = c >> 5, c16 = c & 31;
        *(int4v*)&lb[pix*512 + ((c16*16) ^ ((pix & 15) << 4))] = src[c];
    }
    __syncthreads();
    int pixL = t & 63;
    int cb = (t >> 6) * 64;
    #pragma unroll 1
    for (int i = 0; i < 8; ++i) {
        int ch0 = cb + i*8;
        int4v v = *(const int4v*)&lb[pixL*512 + ((ch0*2) ^ ((pixL & 15) << 4))];
        #pragma unroll
        for (int j = 0; j < 8; ++j) {
            int ch = ch0 + j;
            int word = v[j >> 1];
            int sval = (j & 1) ? (word >> 16) : ((word << 16) >> 16);
            size_t g = (size_t)(n*CH + ch)*HWSZ + p0 + pixL;
            out[g] = fmaf(ab[ch], (float)sval, ab[CH + ch]) + x[g];
        }
    }
}

extern "C" void kernel_launch(void* const* d_in, const int* in_sizes, int n_in,
                              void* d_out, int out_size, void* d_ws, size_t ws_size,
                              hipStream_t stream) {
    const float* x  = (const float*)d_in[0];
    const float* w1 = (const float*)d_in[1];
    const float* g1 = (const float*)d_in[2];
    const float* b1 = (const float*)d_in[3];
    const float* w2 = (const float*)d_in[4];
    const float* g2 = (const float*)d_in[5];
    const float* b2 = (const float*)d_in[6];
    float* out = (float*)d_out;

    char* ws = (char*)d_ws;
    size_t off = 0;
    auto alloc = [&](size_t nbytes) { char* pp = ws + off; off = (off + nbytes + 255) & ~(size_t)255; return pp; };
    int8_t*   apad  = (int8_t*)alloc((size_t)PADPIX*CH);           // 27.6 MB
    int16_t*  cnt   = (int16_t*)alloc((size_t)NPIX*CH*2);          // 51.4 MB
    int8_t*   wq    = (int8_t*)alloc((size_t)2*WQ_CONV);           // 1.2 MB
    float*    alpha = (float*)alloc((size_t)2*CH*4);
    long long* sums = (long long*)alloc((size_t)2*CH*2*8);
    float*    ab    = (float*)alloc((size_t)2*2*CH*4);             // [a1,b1 | a2,b2]

    init_kernel<<<4, 256, 0, stream>>>(sums);
    wqpack_kernel<<<dim3(144, 2), 256, 0, stream>>>(w1, w2, wq);
    alpha_kernel<<<dim3(CH, 2), 256, 0, stream>>>(w1, w2, alpha);
    pack_x_kernel<<<(PADPIX + 255)/256, 256, 0, stream>>>(x, apad);

    conv_kernel<<<784, 256, 0, stream>>>(apad, wq, cnt);
    stats_kernel<<<392, 256, 0, stream>>>(cnt, sums);
    bncoef_kernel<<<1, CH, 0, stream>>>(sums, alpha, g1, b1, ab);

    pack_s_kernel<<<(PADPIX + 255)/256, 256, 0, stream>>>(cnt, ab, apad);
    conv_kernel<<<784, 256, 0, stream>>>(apad, wq + WQ_CONV, cnt);
    stats_kernel<<<392, 256, 0, stream>>>(cnt, sums + 2*CH);
    bncoef_kernel<<<1, CH, 0, stream>>>(sums + 2*CH, alpha + CH, g2, b2, ab + 2*CH);

    final_kernel<<<1568, 256, 0, stream>>>(cnt, x, ab + 2*CH, out);
}

// Round 4
// 262.672 us; speedup vs baseline: 2.0895x; 1.2360x over previous
//
#include <hip/hip_runtime.h>
#include <stdint.h>

// Problem constants (N,C,H,W fixed by the reference)
#define NB 32
#define CH 256
#define HH 56
#define WW 56
#define HWSZ (HH*WW)            // 3136
#define NPIX (NB*HWSZ)          // 100352
#define HP 58
#define WP 58
#define PADPIX (NB*HP*WP)       // 107648
#define NTAPS 9
#define KKE (CH*NTAPS)          // 2304
#define NPIXD 100352.0
#define WQ_CONV (NTAPS*8*8*64*16)   // 589824 bytes of prepacked weights per conv
#define HSTRIDE 272             // halo row stride (non-mult-of-128 -> conflict-free)

typedef int int4v  __attribute__((ext_vector_type(4)));
typedef int int16v __attribute__((ext_vector_type(16)));

// ---------------- init: zero stats accumulators (8-way split) ----------------
__global__ void init_kernel(long long* __restrict__ sums8) {
    int t = blockIdx.x*256 + threadIdx.x;
    if (t < 2*8*512) sums8[t] = 0;     // 2 convs x 8 splits x 256 ch x {sum,sumsq}
}

// ---------------- prepack weights into MFMA B-fragment layout ----------------
// wq[conv][tap][ks][nb][lane][16B]: byte b of lane l = sign(w[o][cin][tap])
// with o = nb*32 + (l&31), cin = ks*32 + (l>>5)*16 + b.
__global__ void wqpack_kernel(const float* __restrict__ w1, const float* __restrict__ w2,
                              int8_t* __restrict__ wq) {
    int t = blockIdx.x*256 + threadIdx.x;     // 144 blocks -> 36864 threads
    int conv = blockIdx.y;
    const float* w = conv ? w2 : w1;
    int lane = t & 63;
    int g = t >> 6;                 // (tap*8+ks)*8+nb
    int nb = g & 7, h = g >> 3;
    int ks = h & 7, tap = h >> 3;
    int o = nb*32 + (lane & 31);
    int cin0 = ks*32 + (lane >> 5)*16;
    int wd[4];
    #pragma unroll
    for (int q = 0; q < 4; ++q) {
        int wv = 0;
        #pragma unroll
        for (int j = 0; j < 4; ++j) {
            float v = w[(size_t)(o*CH + cin0 + q*4 + j)*NTAPS + tap];
            int s = (v > 0.f) ? 1 : ((v < 0.f) ? -1 : 0);
            wv |= (s & 0xff) << (8*j);
        }
        wd[q] = wv;
    }
    *(int4v*)(wq + (size_t)conv*WQ_CONV + (size_t)t*16) = (int4v){wd[0], wd[1], wd[2], wd[3]};
}

// ---------------- alpha[o] = mean |w| over (I,3,3) ----------------
__global__ void alpha_kernel(const float* __restrict__ w1, const float* __restrict__ w2,
                             float* __restrict__ alpha) {
    int o = blockIdx.x; int conv = blockIdx.y;
    const float* w = conv ? w2 : w1;
    float s = 0.f;
    for (int i = threadIdx.x; i < KKE; i += 256) s += fabsf(w[(size_t)o*KKE + i]);
    for (int off = 32; off; off >>= 1) s += __shfl_down(s, off);
    __shared__ float l[4];
    int lane = threadIdx.x & 63, wv = threadIdx.x >> 6;
    if (lane == 0) l[wv] = s;
    __syncthreads();
    if (threadIdx.x == 0) alpha[conv*CH + o] = (l[0]+l[1]+l[2]+l[3]) * (1.f/KKE);
}

// ---------------- pack activations: x -> int8 sign, padded, ch-contiguous ----------------
__global__ void pack_x_kernel(const float* __restrict__ x, int8_t* __restrict__ apad) {
    int p = blockIdx.x*256 + threadIdx.x;
    if (p >= PADPIX) return;
    int n  = p / (HP*WP);
    int r  = p - n*(HP*WP);
    int hp = r / WP, wp = r - hp*WP;
    int4v* dst = (int4v*)(apad + (size_t)p*CH);
    if (hp >= 1 && hp <= HH && wp >= 1 && wp <= WW) {
        const float* xb = x + (size_t)n*CH*HWSZ + (hp-1)*WW + (wp-1);
        #pragma unroll 2
        for (int c16 = 0; c16 < 16; ++c16) {
            int wd[4];
            #pragma unroll
            for (int q = 0; q < 4; ++q) {
                int wv = 0;
                #pragma unroll
                for (int j = 0; j < 4; ++j) {
                    float v = xb[(size_t)(c16*16 + q*4 + j)*HWSZ];
                    int s = (v > 0.f) ? 1 : ((v < 0.f) ? -1 : 0);
                    wv |= (s & 0xff) << (8*j);
                }
                wd[q] = wv;
            }
            dst[c16] = (int4v){wd[0], wd[1], wd[2], wd[3]};
        }
    } else {
        int4v z = {0,0,0,0};
        #pragma unroll
        for (int c16 = 0; c16 < 16; ++c16) dst[c16] = z;
    }
}

// ---------------- pack sign(BN1(cnt)) -> int8, padded ----------------
__global__ void pack_s_kernel(const int16_t* __restrict__ cnt,
                              const float* __restrict__ ab,   // a=ab[0..255], b=ab[256..511]
                              int8_t* __restrict__ apad) {
    int p = blockIdx.x*256 + threadIdx.x;
    if (p >= PADPIX) return;
    int n  = p / (HP*WP);
    int r  = p - n*(HP*WP);
    int hp = r / WP, wp = r - hp*WP;
    int4v* dst = (int4v*)(apad + (size_t)p*CH);
    if (hp >= 1 && hp <= HH && wp >= 1 && wp <= WW) {
        const int4v* cb = (const int4v*)(cnt + ((size_t)n*HWSZ + (hp-1)*WW + (wp-1))*CH);
        #pragma unroll 2
        for (int c16 = 0; c16 < 16; ++c16) {
            int4v u0 = cb[c16*2], u1 = cb[c16*2+1];
            int wd[4];
            #pragma unroll
            for (int q = 0; q < 4; ++q) {
                int wv = 0;
                #pragma unroll
                for (int j = 0; j < 4; ++j) {
                    int e = q*4 + j;                       // 0..15 within this 16-ch group
                    int word = (e < 8) ? u0[e >> 1] : u1[(e-8) >> 1];
                    int sval = (e & 1) ? (word >> 16) : ((word << 16) >> 16);
                    int ch = c16*16 + e;
                    float v = fmaf(ab[ch], (float)sval, ab[CH + ch]);
                    int s = (v > 0.f) ? 1 : ((v < 0.f) ? -1 : 0);
                    wv |= (s & 0xff) << (8*j);
                }
                wd[q] = wv;
            }
            dst[c16] = (int4v){wd[0], wd[1], wd[2], wd[3]};
        }
    } else {
        int4v z = {0,0,0,0};
        #pragma unroll
        for (int c16 = 0; c16 < 16; ++c16) dst[c16] = z;
    }
}

// ---------------- int8 MFMA implicit-GEMM 3x3 conv, fused stats ----------------
// wg = {2 images} x 8x8 pixels x 256 outs.  M=128, N=256, K=2304, fully unrolled K.
// A-load byte offset within halo: tap (dh,dw), k-step ks -> compile-time immediate.
#define AOFF(IT) (((((IT)>>3)/3)*10 + (((IT)>>3)%3))*HSTRIDE + ((IT)&7)*32)

__global__ __launch_bounds__(256, 2) void conv_kernel(
        const int8_t* __restrict__ apad, const int8_t* __restrict__ wq,
        int16_t* __restrict__ cnt, long long* __restrict__ sums8) {
    __shared__ __attribute__((aligned(16))) int8_t halo[200*HSTRIDE];   // 54.4 KB
    int b = blockIdx.x;                           // 784 = 16 image-pairs x 49 tiles
    int tile = b % 49, npair = b / 49;
    int ty = tile / 7, tx = tile % 7;
    int n0 = npair * 2;
    int t = threadIdx.x;

    // stage halo: 200 pixels x 16 chunks of 16B; row stride 272 -> conflict-free
    #pragma unroll 1
    for (int j = 0; j < 13; ++j) {
        int idx = t + j*256;
        if (idx < 3200) {
            int pix = idx >> 4, c16 = idx & 15;
            int img = (pix >= 100) ? 1 : 0;
            int hp = pix - img*100;
            int dr = hp / 10, dc = hp - dr*10;
            const int4v* src = (const int4v*)(apad +
                ((size_t)(((n0+img)*HP + ty*8+dr)*WP + tx*8+dc))*CH + c16*16);
            *(int4v*)&halo[pix*HSTRIDE + c16*16] = *src;
        }
    }
    __syncthreads();

    int lane = t & 63;
    int wv = __builtin_amdgcn_readfirstlane(t >> 6);   // wave-uniform -> SGPR addressing
    int kh = lane >> 5, lr = lane & 31;
    int r0 = lr >> 3, c0 = lr & 7;
    int base0 = (r0*10 + c0)*HSTRIDE + kh*16;     // img0, rows 0..3
    int base1 = base0 + 40*HSTRIDE;               // img0, rows 4..7
    int base2 = base0 + 100*HSTRIDE;              // img1
    int base3 = base0 + 140*HSTRIDE;

    const int8_t* wp0 = wq + wv*2048 + lane*16;
    const int8_t* wp1 = wp0 + 1024;

    int16v acc00, acc01, acc10, acc11, acc20, acc21, acc30, acc31;
    #pragma unroll
    for (int i = 0; i < 16; ++i) {
        acc00[i]=0; acc01[i]=0; acc10[i]=0; acc11[i]=0;
        acc20[i]=0; acc21[i]=0; acc30[i]=0; acc31[i]=0;
    }

    int4v a[2][4], bb[2][2];
    a[0][0] = *(const int4v*)&halo[base0 + AOFF(0)];
    a[0][1] = *(const int4v*)&halo[base1 + AOFF(0)];
    a[0][2] = *(const int4v*)&halo[base2 + AOFF(0)];
    a[0][3] = *(const int4v*)&halo[base3 + AOFF(0)];
    bb[0][0] = *(const int4v*)(wp0);
    bb[0][1] = *(const int4v*)(wp1);

    #pragma unroll
    for (int it = 0; it < 72; ++it) {             // 9 taps x 8 k-steps, FULL unroll
        int cur = it & 1, nxt = cur ^ 1;
        if (it + 1 < 72) {
            a[nxt][0] = *(const int4v*)&halo[base0 + AOFF(it+1)];
            a[nxt][1] = *(const int4v*)&halo[base1 + AOFF(it+1)];
            a[nxt][2] = *(const int4v*)&halo[base2 + AOFF(it+1)];
            a[nxt][3] = *(const int4v*)&halo[base3 + AOFF(it+1)];
            bb[nxt][0] = *(const int4v*)(wp0 + (it+1)*8192);
            bb[nxt][1] = *(const int4v*)(wp1 + (it+1)*8192);
        }
        acc00 = __builtin_amdgcn_mfma_i32_32x32x32_i8(a[cur][0], bb[cur][0], acc00, 0,0,0);
        acc01 = __builtin_amdgcn_mfma_i32_32x32x32_i8(a[cur][0], bb[cur][1], acc01, 0,0,0);
        acc10 = __builtin_amdgcn_mfma_i32_32x32x32_i8(a[cur][1], bb[cur][0], acc10, 0,0,0);
        acc11 = __builtin_amdgcn_mfma_i32_32x32x32_i8(a[cur][1], bb[cur][1], acc11, 0,0,0);
        acc20 = __builtin_amdgcn_mfma_i32_32x32x32_i8(a[cur][2], bb[cur][0], acc20, 0,0,0);
        acc21 = __builtin_amdgcn_mfma_i32_32x32x32_i8(a[cur][2], bb[cur][1], acc21, 0,0,0);
        acc30 = __builtin_amdgcn_mfma_i32_32x32x32_i8(a[cur][3], bb[cur][0], acc30, 0,0,0);
        acc31 = __builtin_amdgcn_mfma_i32_32x32x32_i8(a[cur][3], bb[cur][1], acc31, 0,0,0);
    }

    // epilogue: C layout col=lane&31, row=(reg&3)+8*(reg>>2)+4*(lane>>5)
#define STOREACC(ACC, M, J) do { \
        int ch_ = (wv*2 + (J))*32 + lr; \
        int img_ = (M) >> 1; \
        _Pragma("unroll") \
        for (int reg = 0; reg < 16; ++reg) { \
            int row_ = (reg & 3) + 8*(reg >> 2) + 4*kh; \
            int pm_ = ((M) & 1)*32 + row_; \
            int rr_ = pm_ >> 3, cc_ = pm_ & 7; \
            cnt[(size_t)(((n0+img_)*HH + ty*8 + rr_)*WW + tx*8 + cc_)*CH + ch_] = (int16_t)ACC[reg]; \
        } \
    } while (0)

    STOREACC(acc00, 0, 0); STOREACC(acc01, 0, 1);
    STOREACC(acc10, 1, 0); STOREACC(acc11, 1, 1);
    STOREACC(acc20, 2, 0); STOREACC(acc21, 2, 1);
    STOREACC(acc30, 3, 0); STOREACC(acc31, 3, 1);
#undef STOREACC

    // fused per-channel stats: sum / sumsq over this block's 128 pixels
    int s1a = 0, s2a = 0, s1b = 0, s2b = 0;
    #pragma unroll
    for (int reg = 0; reg < 16; ++reg) {
        int v;
        v = acc00[reg]; s1a += v; s2a += v*v;
        v = acc10[reg]; s1a += v; s2a += v*v;
        v = acc20[reg]; s1a += v; s2a += v*v;
        v = acc30[reg]; s1a += v; s2a += v*v;
        v = acc01[reg]; s1b += v; s2b += v*v;
        v = acc11[reg]; s1b += v; s2b += v*v;
        v = acc21[reg]; s1b += v; s2b += v*v;
        v = acc31[reg]; s1b += v; s2b += v*v;
    }
    s1a += __shfl_down(s1a, 32); s2a += __shfl_down(s2a, 32);
    s1b += __shfl_down(s1b, 32); s2b += __shfl_down(s2b, 32);
    if (lane < 32) {
        long long* sp = sums8 + (size_t)(b & 7)*512;
        int ch0 = wv*64 + lr, ch1 = ch0 + 32;
        atomicAdd((unsigned long long*)&sp[2*ch0],   (unsigned long long)(long long)s1a);
        atomicAdd((unsigned long long*)&sp[2*ch0+1], (unsigned long long)(long long)s2a);
        atomicAdd((unsigned long long*)&sp[2*ch1],   (unsigned long long)(long long)s1b);
        atomicAdd((unsigned long long*)&sp[2*ch1+1], (unsigned long long)(long long)s2b);
    }
}

// ---------------- BN coefficients: BN(alpha*cnt) = a*cnt + b ----------------
__global__ void bncoef_kernel(const long long* __restrict__ sums8,
                              const float* __restrict__ alpha,
                              const float* __restrict__ gamma, const float* __restrict__ beta,
                              float* __restrict__ ab) {
    int o = threadIdx.x;
    long long S1i = 0, S2i = 0;
    #pragma unroll
    for (int k = 0; k < 8; ++k) {
        S1i += sums8[(size_t)k*512 + 2*o];
        S2i += sums8[(size_t)k*512 + 2*o + 1];
    }
    double S1 = (double)S1i, S2 = (double)S2i;
    double mean = S1 / NPIXD;
    double var  = S2 / NPIXD - mean*mean;
    double al   = (double)alpha[o];
    double rs   = 1.0 / sqrt(al*al*var + 1e-5);
    double a    = (double)gamma[o] * al * rs;
    ab[o]      = (float)a;
    ab[CH + o] = (float)((double)beta[o] - a*mean);
}

// ---------------- fused epilogue: out = a2*cnt2 + b2 + x  (LDS transpose) ----------------
__global__ __launch_bounds__(256) void final_kernel(const int16_t* __restrict__ cnt,
        const float* __restrict__ x, const float* __restrict__ ab, float* __restrict__ out) {
    __shared__ int4v lsd4[64*32];                 // 64 pixels x 512B, swizzled
    int8_t* lb = (int8_t*)lsd4;
    int b = blockIdx.x;                           // 1568 = 32 n x 49 tiles
    int n = b / 49, tile = b - n*49;
    int p0 = tile * 64;
    int t = threadIdx.x;
    const int4v* src = (const int4v*)(cnt + ((size_t)n*HWSZ + p0)*CH);
    #pragma unroll
    for (int j = 0; j < 8; ++j) {
        int c = t + j*256;                        // 2048 16B-chunks
        int pix = c >> 5, c16 = c & 31;
        *(int4v*)&lb[pix*512 + ((c16*16) ^ ((pix & 15) << 4))] = src[c];
    }
    __syncthreads();
    int pixL = t & 63;
    int cb = (t >> 6) * 64;
    #pragma unroll 1
    for (int i = 0; i < 8; ++i) {
        int ch0 = cb + i*8;
        int4v v = *(const int4v*)&lb[pixL*512 + ((ch0*2) ^ ((pixL & 15) << 4))];
        #pragma unroll
        for (int j = 0; j < 8; ++j) {
            int ch = ch0 + j;
            int word = v[j >> 1];
            int sval = (j & 1) ? (word >> 16) : ((word << 16) >> 16);
            size_t g = (size_t)(n*CH + ch)*HWSZ + p0 + pixL;
            out[g] = fmaf(ab[ch], (float)sval, ab[CH + ch]) + x[g];
        }
    }
}

extern "C" void kernel_launch(void* const* d_in, const int* in_sizes, int n_in,
                              void* d_out, int out_size, void* d_ws, size_t ws_size,
                              hipStream_t stream) {
    const float* x  = (const float*)d_in[0];
    const float* w1 = (const float*)d_in[1];
    const float* g1 = (const float*)d_in[2];
    const float* b1 = (const float*)d_in[3];
    const float* w2 = (const float*)d_in[4];
    const float* g2 = (const float*)d_in[5];
    const float* b2 = (const float*)d_in[6];
    float* out = (float*)d_out;

    char* ws = (char*)d_ws;
    size_t off = 0;
    auto alloc = [&](size_t nbytes) { char* pp = ws + off; off = (off + nbytes + 255) & ~(size_t)255; return pp; };
    int8_t*   apad  = (int8_t*)alloc((size_t)PADPIX*CH);           // 27.6 MB
    int16_t*  cnt   = (int16_t*)alloc((size_t)NPIX*CH*2);          // 51.4 MB
    int8_t*   wq    = (int8_t*)alloc((size_t)2*WQ_CONV);           // 1.2 MB
    float*    alpha = (float*)alloc((size_t)2*CH*4);
    long long* sums8 = (long long*)alloc((size_t)2*8*512*8);       // 64 KB
    float*    ab    = (float*)alloc((size_t)2*2*CH*4);             // [a1,b1 | a2,b2]

    init_kernel<<<32, 256, 0, stream>>>(sums8);
    wqpack_kernel<<<dim3(144, 2), 256, 0, stream>>>(w1, w2, wq);
    alpha_kernel<<<dim3(CH, 2), 256, 0, stream>>>(w1, w2, alpha);
    pack_x_kernel<<<(PADPIX + 255)/256, 256, 0, stream>>>(x, apad);

    conv_kernel<<<784, 256, 0, stream>>>(apad, wq, cnt, sums8);
    bncoef_kernel<<<1, CH, 0, stream>>>(sums8, alpha, g1, b1, ab);

    pack_s_kernel<<<(PADPIX + 255)/256, 256, 0, stream>>>(cnt, ab, apad);
    conv_kernel<<<784, 256, 0, stream>>>(apad, wq + WQ_CONV, cnt, sums8 + 8*512);
    bncoef_kernel<<<1, CH, 0, stream>>>(sums8 + 8*512, alpha + CH, g2, b2, ab + 2*CH);

    final_kernel<<<1568, 256, 0, stream>>>(cnt, x, ab + 2*CH, out);
}